// Round 4
// baseline (711.954 us; speedup 1.0000x reference)
//
#include <hip/hip_runtime.h>
#include <math.h>

#define P1 68    // fc1_chain LDS pitch (floats): 68%32=4 -> reads <=2-way, affine
#define PA 68    // fc2 A pitch
#define PB 132   // fc2 B pitch (132%32=4)

// 64x64 x 64k micro-kernel: A [tok][k] pitch P1, B [k][o] pitch P1.
// All LDS addresses are base + compile-time immediate (k fully unrolled):
// zero per-k address VALU. k ascending -> same accumulation order as before.
__device__ __forceinline__ void mm64(const float* __restrict__ sA,
                                     const float* __restrict__ sB,
                                     int r0, int c0, float acc[4][4]) {
#pragma unroll
    for (int kq = 0; kq < 16; ++kq) {
        float a[4][4];
#pragma unroll
        for (int i = 0; i < 4; ++i) {
            const float4 v = *(const float4*)(sA + (r0 + i) * P1 + kq * 4);
            a[i][0] = v.x; a[i][1] = v.y; a[i][2] = v.z; a[i][3] = v.w;
        }
#pragma unroll
        for (int kk = 0; kk < 4; ++kk) {
            const float4 b = *(const float4*)(sB + (kq * 4 + kk) * P1 + c0);
            const float bb[4] = {b.x, b.y, b.z, b.w};
#pragma unroll
            for (int i = 0; i < 4; ++i)
#pragma unroll
                for (int j = 0; j < 4; ++j)
                    acc[i][j] = fmaf(a[i][kk], bb[j], acc[i][j]);
        }
    }
}

// ---------------------------------------------------------------------------
// Kernel AB: fc1 (768->64) + 8x 64x64 chain + residual + exact GELU.
// Round-1 geometry (T=64 tok, 256 thr, 4x4 micro, 4 blocks/CU). Affine
// token-major LDS (immediate ds_read offsets, no XOR on the read path,
// no act transpose on the inter-layer store).
// ---------------------------------------------------------------------------
__global__ __launch_bounds__(256, 4) void k_fc1_chain(
    const float* __restrict__ x, const float* __restrict__ fc1_w,
    const float* __restrict__ fc1_b, const float* __restrict__ conv_w,
    const float* __restrict__ conv_b, float* __restrict__ xs)
{
    __shared__ float sAct[64 * P1];  // [tok][k or ch]
    __shared__ float sW[64 * P1];    // [k][o]

    const int tid = threadIdx.x;
    const int tx = tid & 15;
    const int ty = tid >> 4;
    const int c0 = tx * 4;     // out-ch base (compute + W staging k-quad)
    const int r0 = ty * 4;     // token base (compute + W staging o-rows)
    const int t0 = blockIdx.x * 64;

    const int arow = tid >> 2; // A staging row 0..63
    const int aq   = tid & 3;  // A staging quad base (quads aq+4j)

    float4 ar[4];
    float wr[4][4];
    float acc[4][4];

    // ---- preload fc1 tile 0 ----
#pragma unroll
    for (int j = 0; j < 4; ++j)
        ar[j] = *(const float4*)(x + (size_t)(t0 + arow) * 768 + (aq + 4 * j) * 4);
#pragma unroll
    for (int i = 0; i < 4; ++i) {
        const float4 v = *(const float4*)(fc1_w + (size_t)(r0 + i) * 768 + c0);
        wr[i][0] = v.x; wr[i][1] = v.y; wr[i][2] = v.z; wr[i][3] = v.w;
    }
#pragma unroll
    for (int i = 0; i < 4; ++i)
#pragma unroll
        for (int j = 0; j < 4; ++j) acc[i][j] = 0.f;

    // ---- fc1: K = 768 in 12 tiles ----
    for (int t = 0; t < 12; ++t) {
        // A: straight copy (no transpose); W: register-transposed b128 writes
#pragma unroll
        for (int j = 0; j < 4; ++j)
            *(float4*)(sAct + arow * P1 + (aq + 4 * j) * 4) = ar[j];
#pragma unroll
        for (int j = 0; j < 4; ++j)
            *(float4*)(sW + (c0 + j) * P1 + r0) =
                make_float4(wr[0][j], wr[1][j], wr[2][j], wr[3][j]);
        __syncthreads();

        if (t < 11) {  // prefetch next K-tile under compute
            const int k0 = (t + 1) * 64;
#pragma unroll
            for (int j = 0; j < 4; ++j)
                ar[j] = *(const float4*)(x + (size_t)(t0 + arow) * 768 + k0 + (aq + 4 * j) * 4);
#pragma unroll
            for (int i = 0; i < 4; ++i) {
                const float4 v = *(const float4*)(fc1_w + (size_t)(r0 + i) * 768 + k0 + c0);
                wr[i][0] = v.x; wr[i][1] = v.y; wr[i][2] = v.z; wr[i][3] = v.w;
            }
        } else {       // prefetch chain W0 instead
#pragma unroll
            for (int i = 0; i < 4; ++i) {
                const float4 v = *(const float4*)(conv_w + (r0 + i) * 64 + c0);
                wr[i][0] = v.x; wr[i][1] = v.y; wr[i][2] = v.z; wr[i][3] = v.w;
            }
        }

        mm64(sAct, sW, r0, c0, acc);
        __syncthreads();
    }

    // fc1 bias -> act into sAct (token-major, direct b128); W0 -> sW
    {
        const float4 b4 = *(const float4*)(fc1_b + c0);
#pragma unroll
        for (int i = 0; i < 4; ++i)
            *(float4*)(sAct + (r0 + i) * P1 + c0) =
                make_float4(acc[i][0] + b4.x, acc[i][1] + b4.y,
                            acc[i][2] + b4.z, acc[i][3] + b4.w);
    }
#pragma unroll
    for (int j = 0; j < 4; ++j)
        *(float4*)(sW + (c0 + j) * P1 + r0) =
            make_float4(wr[0][j], wr[1][j], wr[2][j], wr[3][j]);
    __syncthreads();

    // ---- chain: 8 layers, in-place act ----
    float res[4][4];
    for (int l = 0; l < 8; ++l) {
        if (l < 7) {  // prefetch W_{l+1} under compute
#pragma unroll
            for (int i = 0; i < 4; ++i) {
                const float4 v = *(const float4*)(conv_w + (l + 1) * 4096 + (r0 + i) * 64 + c0);
                wr[i][0] = v.x; wr[i][1] = v.y; wr[i][2] = v.z; wr[i][3] = v.w;
            }
        }
#pragma unroll
        for (int i = 0; i < 4; ++i)
#pragma unroll
            for (int j = 0; j < 4; ++j) acc[i][j] = 0.f;

        mm64(sAct, sW, r0, c0, acc);

        {
            const float4 b4 = *(const float4*)(conv_b + l * 64 + c0);
#pragma unroll
            for (int i = 0; i < 4; ++i) {
                acc[i][0] += b4.x; acc[i][1] += b4.y;
                acc[i][2] += b4.z; acc[i][3] += b4.w;
            }
        }
        if (l == 5) {
#pragma unroll
            for (int i = 0; i < 4; ++i)
#pragma unroll
                for (int j = 0; j < 4; ++j) res[i][j] = acc[i][j];
        }
        if (l < 7) {
            __syncthreads();  // all reads of sAct/sW done
#pragma unroll
            for (int i = 0; i < 4; ++i)
                *(float4*)(sAct + (r0 + i) * P1 + c0) =
                    make_float4(acc[i][0], acc[i][1], acc[i][2], acc[i][3]);
#pragma unroll
            for (int j = 0; j < 4; ++j)
                *(float4*)(sW + (c0 + j) * P1 + r0) =
                    make_float4(wr[0][j], wr[1][j], wr[2][j], wr[3][j]);
            __syncthreads();
        }
    }

    // epilogue: residual (h after layer 5) + exact GELU, token-major store
#pragma unroll
    for (int i = 0; i < 4; ++i) {
        float4 g4;
        float v;
        v = acc[i][0] + res[i][0]; g4.x = 0.5f * v * (1.f + erff(v * 0.70710678118654752f));
        v = acc[i][1] + res[i][1]; g4.y = 0.5f * v * (1.f + erff(v * 0.70710678118654752f));
        v = acc[i][2] + res[i][2]; g4.z = 0.5f * v * (1.f + erff(v * 0.70710678118654752f));
        v = acc[i][3] + res[i][3]; g4.w = 0.5f * v * (1.f + erff(v * 0.70710678118654752f));
        *(float4*)(xs + (size_t)(t0 + r0 + i) * 64 + c0) = g4;
    }
}

// ---------------------------------------------------------------------------
// Kernel C: qkv. 4 output-channel groups of 12. xs read planar (free reshape).
// ---------------------------------------------------------------------------
__global__ __launch_bounds__(256) void k_qkv(
    const float* __restrict__ xs, const float* __restrict__ qkv_w,
    const float* __restrict__ qkv_b, float* __restrict__ qkv)
{
    __shared__ float wq[12 * 64];
    __shared__ float qb[12];
    const int tid = threadIdx.x;
    const int g = blockIdx.y;
    for (int i = tid; i < 768; i += 256) wq[i] = qkv_w[g * 768 + i];
    if (tid < 12) qb[tid] = qkv_b[g * 12 + tid];
    __syncthreads();

    const int p = blockIdx.x * 256 + tid;
    float acc[12];
#pragma unroll
    for (int n = 0; n < 12; ++n) acc[n] = qb[n];

    for (int c = 0; c < 64; c += 4) {
        const float xv0 = xs[(c + 0) * 65536 + p];
        const float xv1 = xs[(c + 1) * 65536 + p];
        const float xv2 = xs[(c + 2) * 65536 + p];
        const float xv3 = xs[(c + 3) * 65536 + p];
#pragma unroll
        for (int n = 0; n < 12; ++n) {
            const float4 w4 = *(const float4*)(wq + n * 64 + c);
            acc[n] += xv0 * w4.x + xv1 * w4.y + xv2 * w4.z + xv3 * w4.w;
        }
    }
#pragma unroll
    for (int n = 0; n < 12; ++n) qkv[(size_t)(g * 12 + n) * 65536 + p] = acc[n];
}

// ---------------------------------------------------------------------------
// Kernel D: shift-conv + dw-conv + rpb + softmax(9) + weighted V, then proj.
// One thread per (pixel, head): 32 px x 8 heads per 256-thread block.
// ---------------------------------------------------------------------------
__global__ __launch_bounds__(256) void k_attn(
    const float* __restrict__ qkv, const float* __restrict__ dep1_w,
    const float* __restrict__ dep_b, const float* __restrict__ dep1_b,
    const float* __restrict__ rpb, const float* __restrict__ proj_w,
    const float* __restrict__ proj_b, float* __restrict__ obuf)
{
    __shared__ float s_d1w[162];
    __shared__ float s_db[18];
    __shared__ float s_d1b[18];
    __shared__ float s_rpb[72];
    __shared__ float s_pw[1024];
    __shared__ float s_pb[64];
    __shared__ float s_o[32 * 17];

    const int tid = threadIdx.x;
    if (tid < 162) s_d1w[tid] = dep1_w[tid];
    if (tid < 18) { s_db[tid] = dep_b[tid]; s_d1b[tid] = dep1_b[tid]; }
    if (tid < 72) s_rpb[tid] = rpb[tid];
    for (int i = tid; i < 1024; i += 256) s_pw[i] = proj_w[i];
    if (tid < 64) s_pb[tid] = proj_b[tid];
    __syncthreads();

    const int px = tid & 31;
    const int nh = tid >> 5;
    const int p = blockIdx.x * 32 + px;
    const int h = p >> 11;
    const int w = p & 2047;

    int np[9];
    float vmask[9];
#pragma unroll
    for (int t = 0; t < 9; ++t) {
        const int dh = t / 3 - 1, dw = t % 3 - 1;
        const int hh = h + dh, ww = w + dw;
        const bool ok = ((unsigned)hh < 32u) && ((unsigned)ww < 2048u);
        np[t] = ok ? (hh * 2048 + ww) : p;
        vmask[t] = ok ? 1.f : 0.f;
    }

    const float* base = qkv + nh * 6 * 65536;
    const float q0 = base[p];
    const float q1 = base[65536 + p];

    float kn[2][9];
#pragma unroll
    for (int c = 0; c < 2; ++c)
#pragma unroll
        for (int t = 0; t < 9; ++t)
            kn[c][t] = base[(2 + c) * 65536 + np[t]] * vmask[t];

    float lg[9];
#pragma unroll
    for (int i = 0; i < 9; ++i) {
        float s = 0.f;
#pragma unroll
        for (int c = 0; c < 2; ++c) {
            const int o = c * 9 + i;
            float conv = 0.f;
#pragma unroll
            for (int t = 0; t < 9; ++t) conv = fmaf(kn[c][t], s_d1w[o * 9 + t], conv);
            const float k6 = kn[c][i] + conv + s_db[o] + s_d1b[o] + s_rpb[nh * 9 + i];
            s = fmaf((c == 0 ? q0 : q1), k6, s);
        }
        lg[i] = s * 0.35355339059327373f;
    }
    float m = lg[0];
#pragma unroll
    for (int i = 1; i < 9; ++i) m = fmaxf(m, lg[i]);
    float sum = 0.f;
#pragma unroll
    for (int i = 0; i < 9; ++i) { lg[i] = expf(lg[i] - m); sum += lg[i]; }
    const float inv = 1.f / sum;

    float vn[2][9];
#pragma unroll
    for (int c = 0; c < 2; ++c)
#pragma unroll
        for (int t = 0; t < 9; ++t)
            vn[c][t] = base[(4 + c) * 65536 + np[t]] * vmask[t];

#pragma unroll
    for (int c = 0; c < 2; ++c) {
        float ov = 0.f;
#pragma unroll
        for (int i = 0; i < 9; ++i) {
            const int o = c * 9 + i;
            float conv = 0.f;
#pragma unroll
            for (int t = 0; t < 9; ++t) conv = fmaf(vn[c][t], s_d1w[o * 9 + t], conv);
            const float v6 = vn[c][i] + conv + s_db[o] + s_d1b[o];
            ov = fmaf(lg[i], v6, ov);
        }
        s_o[px * 17 + nh * 2 + c] = ov * inv;
    }
    __syncthreads();

    const int dg = tid >> 5;
    float my[16];
#pragma unroll
    for (int j = 0; j < 16; ++j) my[j] = s_o[px * 17 + j];
#pragma unroll
    for (int k = 0; k < 8; ++k) {
        const int d = dg * 8 + k;
        float s = s_pb[d];
#pragma unroll
        for (int j = 0; j < 16; ++j) s = fmaf(my[j], s_pw[d * 16 + j], s);
        obuf[(size_t)d * 65536 + p] = s;
    }
}

// ---------------------------------------------------------------------------
// Kernel E: fc2 (64->768) + bias + residual. Independent-block grid (1024,6),
// affine LDS layout (immediate ds_read offsets).
// ---------------------------------------------------------------------------
__global__ __launch_bounds__(256) void k_fc2(
    const float* __restrict__ ot, const float* __restrict__ fc2_w,
    const float* __restrict__ fc2_b, const float* __restrict__ x,
    float* __restrict__ out)
{
    __shared__ float sA[64 * PA];   // [tok][k]
    __shared__ float sB[64 * PB];   // [k][n] (128 n)

    const int tid = threadIdx.x;
    const int tx = tid & 15;
    const int ty = tid >> 4;
    const int t0 = blockIdx.x * 64;
    const int n0 = blockIdx.y * 128;
    const int c0 = tx * 4;
    const int r0 = ty * 4;
    const int arow = tid >> 2;
    const int aq   = tid & 3;

    // A: straight copy (ot is token-major); B: register-transposed
    float4 av[4];
#pragma unroll
    for (int j = 0; j < 4; ++j)
        av[j] = *(const float4*)(ot + (size_t)(t0 + arow) * 64 + (aq + 4 * j) * 4);
    float bw[8][4];
#pragma unroll
    for (int i = 0; i < 8; ++i) {
        const float4 v = *(const float4*)(fc2_w + (size_t)(n0 + ty * 8 + i) * 64 + c0);
        bw[i][0] = v.x; bw[i][1] = v.y; bw[i][2] = v.z; bw[i][3] = v.w;
    }
#pragma unroll
    for (int j = 0; j < 4; ++j)
        *(float4*)(sA + arow * PA + (aq + 4 * j) * 4) = av[j];
#pragma unroll
    for (int j = 0; j < 4; ++j) {
        *(float4*)(sB + (c0 + j) * PB + ty * 8) =
            make_float4(bw[0][j], bw[1][j], bw[2][j], bw[3][j]);
        *(float4*)(sB + (c0 + j) * PB + ty * 8 + 4) =
            make_float4(bw[4][j], bw[5][j], bw[6][j], bw[7][j]);
    }
    __syncthreads();

    float acc[4][8];
#pragma unroll
    for (int i = 0; i < 4; ++i)
#pragma unroll
        for (int j = 0; j < 8; ++j) acc[i][j] = 0.f;

#pragma unroll
    for (int kq = 0; kq < 16; ++kq) {
        float a[4][4];
#pragma unroll
        for (int i = 0; i < 4; ++i) {
            const float4 v = *(const float4*)(sA + (r0 + i) * PA + kq * 4);
            a[i][0] = v.x; a[i][1] = v.y; a[i][2] = v.z; a[i][3] = v.w;
        }
#pragma unroll
        for (int kk = 0; kk < 4; ++kk) {
            const float4 b0 = *(const float4*)(sB + (kq * 4 + kk) * PB + c0);
            const float4 b1 = *(const float4*)(sB + (kq * 4 + kk) * PB + 64 + c0);
            const float b[8] = {b0.x, b0.y, b0.z, b0.w, b1.x, b1.y, b1.z, b1.w};
#pragma unroll
            for (int i = 0; i < 4; ++i)
#pragma unroll
                for (int j = 0; j < 8; ++j)
                    acc[i][j] = fmaf(a[i][kk], b[j], acc[i][j]);
        }
    }

    float bb[8];
#pragma unroll
    for (int j = 0; j < 4; ++j) { bb[j] = fc2_b[n0 + c0 + j]; bb[4 + j] = fc2_b[n0 + 64 + c0 + j]; }

#pragma unroll
    for (int i = 0; i < 4; ++i) {
        const size_t off = (size_t)(t0 + r0 + i) * 768 + n0;
        const float4 x0 = *(const float4*)(x + off + c0);
        const float4 x1 = *(const float4*)(x + off + 64 + c0);
        float4 o0, o1;
        o0.x = acc[i][0] + bb[0] + x0.x;
        o0.y = acc[i][1] + bb[1] + x0.y;
        o0.z = acc[i][2] + bb[2] + x0.z;
        o0.w = acc[i][3] + bb[3] + x0.w;
        o1.x = acc[i][4] + bb[4] + x1.x;
        o1.y = acc[i][5] + bb[5] + x1.y;
        o1.z = acc[i][6] + bb[6] + x1.z;
        o1.w = acc[i][7] + bb[7] + x1.w;
        *(float4*)(out + off + c0) = o0;
        *(float4*)(out + off + 64 + c0) = o1;
    }
}

// ---------------------------------------------------------------------------
extern "C" void kernel_launch(void* const* d_in, const int* in_sizes, int n_in,
                              void* d_out, int out_size, void* d_ws, size_t ws_size,
                              hipStream_t stream) {
    const float* x      = (const float*)d_in[0];
    const float* fc1_w  = (const float*)d_in[1];
    const float* fc1_b  = (const float*)d_in[2];
    const float* conv_w = (const float*)d_in[3];
    const float* conv_b = (const float*)d_in[4];
    const float* qkv_w  = (const float*)d_in[5];
    const float* qkv_b  = (const float*)d_in[6];
    const float* dep1_w = (const float*)d_in[7];
    const float* dep_b  = (const float*)d_in[8];
    const float* dep1_b = (const float*)d_in[9];
    const float* rpb    = (const float*)d_in[10];
    const float* proj_w = (const float*)d_in[11];
    const float* proj_b = (const float*)d_in[12];
    const float* fc2_w  = (const float*)d_in[13];
    const float* fc2_b  = (const float*)d_in[14];

    float* ws   = (float*)d_ws;
    float* xs   = ws;                 // 64*65536
    float* qkv  = ws + 4194304;       // 48*65536
    float* obuf = ws + 7340032;       // 64*65536
    float* out  = (float*)d_out;

    k_fc1_chain<<<dim3(1024), dim3(256), 0, stream>>>(x, fc1_w, fc1_b, conv_w, conv_b, xs);
    k_qkv<<<dim3(256, 4), dim3(256), 0, stream>>>(xs, qkv_w, qkv_b, qkv);
    k_attn<<<dim3(2048), dim3(256), 0, stream>>>(qkv, dep1_w, dep_b, dep1_b, rpb,
                                                 proj_w, proj_b, obuf);
    k_fc2<<<dim3(1024, 6), dim3(256), 0, stream>>>(obuf, fc2_w, fc2_b, x, out);
}